// Round 10
// baseline (82.137 us; speedup 1.0000x reference)
//
#include <hip/hip_runtime.h>

typedef float f32x4 __attribute__((ext_vector_type(4)));
typedef short bf16x8 __attribute__((ext_vector_type(8)));

__device__ inline short f2bf(float x) {               // RNE float->bf16 bits
    unsigned u = __float_as_uint(x);
    unsigned r = (u + 0x7fffu + ((u >> 16) & 1u)) >> 16;
    return (short)r;
}
__device__ inline float bf2f(short h) {
    return __uint_as_float(((unsigned)(unsigned short)h) << 16);
}

// Prep: pack rec -> A-slots [-2qh(3), -2ql(3), -2qh(3), 1, 1, 0...] + qw fp32;
//       pack data -> B-slots [ph(3), ph(3), pl(3), pwh, pwl, 0...].
// A and B share ONE slot space: HW pairs A-reg j with B-reg j, so the dot is
// correct for ANY lane->k mapping as long as both operands use the same one.
__global__ __launch_bounds__(256)
void chamfer_prep(const float* __restrict__ rec, const float* __restrict__ data,
                  bf16x8* __restrict__ Apack, bf16x8* __restrict__ Bpack,
                  float* __restrict__ qw, int N, int M, int B)
{
    const int i = blockIdx.x * 256 + threadIdx.x;
    const int tot0 = B * N;
    const int tot  = B * (N + M);
    if (i >= tot) return;
    const bf16x8 z8 = {0,0,0,0,0,0,0,0};
    const short ONE = 0x3F80;
    if (i < tot0) {                       // rec point -> A row
        const float* p = rec + (size_t)i * 3;
        const float x = p[0], y = p[1], z = p[2];
        qw[i] = fmaf(x, x, fmaf(y, y, z * z));
        const short hx = f2bf(-2.f * bf2f(f2bf(x)));
        const short hy = f2bf(-2.f * bf2f(f2bf(y)));
        const short hz = f2bf(-2.f * bf2f(f2bf(z)));
        const short lx = f2bf(-2.f * (x - bf2f(f2bf(x))));
        const short ly = f2bf(-2.f * (y - bf2f(f2bf(y))));
        const short lz = f2bf(-2.f * (z - bf2f(f2bf(z))));
        bf16x8 w0 = {hx, hy, hz, lx, ly, lz, hx, hy};
        bf16x8 w1 = {hz, ONE, ONE, 0, 0, 0, 0, 0};
        bf16x8* o = Apack + (size_t)i * 4;
        o[0] = w0; o[1] = w1; o[2] = z8; o[3] = z8;
    } else {                              // data point -> B col
        const int j = i - tot0;
        const float* p = data + (size_t)j * 3;
        const float x = p[0], y = p[1], z = p[2];
        const float pw = fmaf(x, x, fmaf(y, y, z * z));
        const short hx = f2bf(x), hy = f2bf(y), hz = f2bf(z);
        const short lx = f2bf(x - bf2f(hx));
        const short ly = f2bf(y - bf2f(hy));
        const short lz = f2bf(z - bf2f(hz));
        const short pwh = f2bf(pw);
        const short pwl = f2bf(pw - bf2f(pwh));
        bf16x8 w0 = {hx, hy, hz, hx, hy, hz, lx, ly};
        bf16x8 w1 = {lz, pwh, pwl, 0, 0, 0, 0, 0};
        bf16x8* o = Bpack + (size_t)j * 4;
        o[0] = w0; o[1] = w1; o[2] = z8; o[3] = z8;
    }
}

// Stage 1: one MFMA pass over the full B x N x M distance matrix.
// Block = (batch b, 128-row Q-tile qb, M-half mh); 4 waves split m-tiles.
// D (C-layout: col=lane&15, row=(lane>>4)*4+reg, m89-verified) is the FULL
// distance (C-in = qw fp32); epilogue is mins only.
__global__ __launch_bounds__(256, 2)
void chamfer_mfma_kernel(const bf16x8* __restrict__ Apack,
                         const bf16x8* __restrict__ Bpack,
                         const float* __restrict__ qw,
                         float* __restrict__ colpart,   // [B*QB][M]
                         float* __restrict__ rowpart,   // [B*QB*2][128]
                         int N, int M, int B)
{
    __shared__ float lred[512];
    const int QB  = N >> 7;
    const int blk = blockIdx.x;
    const int mh  = blk & 1;
    const int qb  = (blk >> 1) % QB;
    const int b   = blk / (2 * QB);
    const int tid = threadIdx.x;
    const int wave = tid >> 6, lane = tid & 63;
    const int g = lane >> 4, c = lane & 15;
    const int row0 = qb * 128;

    bf16x8 a[8];
    f32x4 qwc[8], rmin[8];
    #pragma unroll
    for (int rt = 0; rt < 8; ++rt) {
        a[rt]   = Apack[(size_t)(b * N + row0 + rt * 16 + c) * 4 + g];
        qwc[rt] = *(const f32x4*)(qw + b * N + row0 + rt * 16 + g * 4);
        rmin[rt] = f32x4{3.4e38f, 3.4e38f, 3.4e38f, 3.4e38f};
    }

    const int TPH = M >> 5;               // m-tiles per half
    for (int t = wave; t < TPH; t += 4) {
        const int mt = mh * TPH + t;
        const bf16x8 bf = Bpack[(size_t)(b * M + mt * 16 + c) * 4 + g];
        float cA = 3.4e38f, cB = 3.4e38f;
        #pragma unroll
        for (int rt = 0; rt < 8; ++rt) {
            f32x4 d = __builtin_amdgcn_mfma_f32_16x16x32_bf16(a[rt], bf, qwc[rt], 0, 0, 0);
            rmin[rt].x = fminf(rmin[rt].x, d.x);
            rmin[rt].y = fminf(rmin[rt].y, d.y);
            rmin[rt].z = fminf(rmin[rt].z, d.z);
            rmin[rt].w = fminf(rmin[rt].w, d.w);
            if (rt & 1) { cB = fminf(fminf(d.x, d.y), cB); cB = fminf(fminf(d.z, d.w), cB); }
            else        { cA = fminf(fminf(d.x, d.y), cA); cA = fminf(fminf(d.z, d.w), cA); }
        }
        float cm = fminf(cA, cB);
        cm = fminf(cm, __shfl_xor(cm, 16));
        cm = fminf(cm, __shfl_xor(cm, 32));
        if (lane < 16)
            colpart[(size_t)(b * QB + qb) * M + mt * 16 + lane] = cm;
    }

    // row-min finalize: reduce across 16 c-lanes (in-wave), then 4 waves (LDS)
    #pragma unroll
    for (int rt = 0; rt < 8; ++rt) {
        #pragma unroll
        for (int i = 0; i < 4; ++i) {
            float rm = (i == 0) ? rmin[rt].x : (i == 1) ? rmin[rt].y
                     : (i == 2) ? rmin[rt].z : rmin[rt].w;
            rm = fminf(rm, __shfl_xor(rm, 1));
            rm = fminf(rm, __shfl_xor(rm, 2));
            rm = fminf(rm, __shfl_xor(rm, 4));
            rm = fminf(rm, __shfl_xor(rm, 8));
            if (c == 0) lred[wave * 128 + rt * 16 + g * 4 + i] = rm;
        }
    }
    __syncthreads();
    if (tid < 128) {
        float v = fminf(fminf(lred[tid], lred[128 + tid]),
                        fminf(lred[256 + tid], lred[384 + tid]));
        rowpart[(size_t)blk * 128 + tid] = v;
    }
}

// Stage 2: finish both directions; one block-sum per 256 queries.
__global__ __launch_bounds__(256)
void chamfer_stage2(const float* __restrict__ colpart,
                    const float* __restrict__ rowpart,
                    float* __restrict__ bsums, int N, int M, int B)
{
    __shared__ float wsum[4];
    const int QB = N >> 7;
    const int nColBlk = (B * M) >> 8;
    const int tid = threadIdx.x, blk = blockIdx.x;
    float d;
    if (blk < nColBlk) {
        const int gid = blk * 256 + tid;
        const int b = gid / M, m = gid - b * M;
        const float* cp = colpart + (size_t)b * QB * M + m;
        float m0 = 3.4e38f, m1 = 3.4e38f, m2 = 3.4e38f, m3 = 3.4e38f;
        for (int q = 0; q + 4 <= QB; q += 4) {
            m0 = fminf(m0, cp[(size_t)(q + 0) * M]);
            m1 = fminf(m1, cp[(size_t)(q + 1) * M]);
            m2 = fminf(m2, cp[(size_t)(q + 2) * M]);
            m3 = fminf(m3, cp[(size_t)(q + 3) * M]);
        }
        d = fmaxf(fminf(fminf(m0, m1), fminf(m2, m3)), 0.f);
    } else {
        const int gid = (blk - nColBlk) * 256 + tid;
        const int b = gid / N, n = gid - b * N;
        const int qb = n >> 7, nl = n & 127;
        const float* rp = rowpart + ((size_t)(b * QB + qb) * 2) * 128 + nl;
        d = fmaxf(fminf(rp[0], rp[128]), 0.f);
    }
    for (int off = 32; off; off >>= 1) d += __shfl_down(d, off);
    if ((tid & 63) == 0) wsum[tid >> 6] = d;
    __syncthreads();
    if (tid == 0)
        bsums[blk] = wsum[0] + wsum[1] + wsum[2] + wsum[3];
}

// Finalize: mean_b( max(rowsum_b/N, colsum_b/M) )
__global__ __launch_bounds__(256)
void chamfer_finalize(const float* __restrict__ bsums, float* __restrict__ out,
                      int N, int M, int B)
{
    __shared__ float seg[16];
    const int tid = threadIdx.x;
    const int cb = M >> 8, rb = N >> 8, nColBlk = (B * M) >> 8;
    if (tid < 2 * B) {
        const int dir = tid / B, b = tid % B;
        float s = 0.f;
        if (dir == 0) for (int i = 0; i < cb; ++i) s += bsums[b * cb + i];
        else          for (int i = 0; i < rb; ++i) s += bsums[nColBlk + b * rb + i];
        seg[tid] = s;
    }
    __syncthreads();
    if (tid == 0) {
        float acc = 0.f;
        for (int b = 0; b < B; ++b)
            acc += fmaxf(seg[B + b] / (float)N, seg[b] / (float)M);
        out[0] = acc / (float)B;
    }
}

extern "C" void kernel_launch(void* const* d_in, const int* in_sizes, int n_in,
                              void* d_out, int out_size, void* d_ws, size_t ws_size,
                              hipStream_t stream)
{
    const float* rec  = (const float*)d_in[0];
    const float* data = (const float*)d_in[1];
    const int B = 4;
    const int N = in_sizes[0] / (B * 3);
    const int M = in_sizes[1] / (B * 3);
    const int QB = N >> 7;

    // ws: Apack 2MB | Bpack 2MB | colpart 8.4MB | rowpart 256KB | qw 128KB | bsums
    char* w = (char*)d_ws;
    bf16x8* Apack = (bf16x8*)w;            w += (size_t)B * N * 64;
    bf16x8* Bpack = (bf16x8*)w;            w += (size_t)B * M * 64;
    float* colpart = (float*)w;            w += (size_t)B * QB * M * 4;
    float* rowpart = (float*)w;            w += (size_t)B * QB * 2 * 128 * 4;
    float* qw = (float*)w;                 w += (size_t)B * N * 4;
    float* bsums = (float*)w;

    const int tot = B * (N + M);
    chamfer_prep<<<(tot + 255) / 256, 256, 0, stream>>>(rec, data, Apack, Bpack,
                                                        qw, N, M, B);
    chamfer_mfma_kernel<<<B * QB * 2, 256, 0, stream>>>(Apack, Bpack, qw,
                                                        colpart, rowpart, N, M, B);
    const int nblk2 = (B * (M + N)) >> 8;
    chamfer_stage2<<<nblk2, 256, 0, stream>>>(colpart, rowpart, bsums, N, M, B);
    chamfer_finalize<<<1, 256, 0, stream>>>(bsums, (float*)d_out, N, M, B);
}

// Round 11
// 62.286 us; speedup vs baseline: 1.3187x; 1.3187x over previous
//
#include <hip/hip_runtime.h>

typedef float f32x16 __attribute__((ext_vector_type(16)));
typedef short bf16x8 __attribute__((ext_vector_type(8)));

__device__ inline short f2bf(float x) {               // RNE float->bf16 bits
    unsigned u = __float_as_uint(x);
    unsigned r = (u + 0x7fffu + ((u >> 16) & 1u)) >> 16;
    return (short)r;
}
__device__ inline float bf2f(short h) {
    return __uint_as_float(((unsigned)(unsigned short)h) << 16);
}
// order-preserving float->uint key (uint min == float min), and inverse
__device__ inline unsigned fkey(float f) {
    unsigned u = __float_as_uint(f);
    return ((int)u < 0) ? ~u : (u | 0x80000000u);
}
__device__ inline float finv(unsigned u) {
    return ((int)u < 0) ? __uint_as_float(u & 0x7fffffffu)
                        : __uint_as_float(~u);
}
__device__ inline float vmin16(f32x16 v) {
    float a = fminf(fminf(v[0], v[1]), fminf(v[2], v[3]));
    float b = fminf(fminf(v[4], v[5]), fminf(v[6], v[7]));
    float c = fminf(fminf(v[8], v[9]), fminf(v[10], v[11]));
    float d = fminf(fminf(v[12], v[13]), fminf(v[14], v[15]));
    return fminf(fminf(a, b), fminf(c, d));
}

// K-slot map (k = 8*half + j), d = qw + pw - 2(qh+ql).(ph+pl) [ql.pl dropped]:
//  k0-2 : A=-2qh  B=ph  | k3-5: A=-2ql B=ph | k6,7: A=qwh,qwl B=1,1
//  k8-10: A=-2qh  B=pl  | k11,12: A=1,1 B=pwh,pwl | k13-15: 0
// A and B use the SAME (half,j) slot space -> layout-mapping agnostic
// (r9-validated trick at 16x16, extended to the 32x32 half dimension).
__global__ __launch_bounds__(256)
void chamfer_prep(const float* __restrict__ rec, const float* __restrict__ data,
                  bf16x8* __restrict__ Apack, bf16x8* __restrict__ Bpack,
                  int N, int M, int B)
{
    const int i = blockIdx.x * 256 + threadIdx.x;
    const int tot0 = B * N, tot = tot0 + B * M;
    if (i >= tot) return;
    const short ONE = 0x3F80;
    if (i < tot0) {                       // rec point -> A fragments
        const float* p = rec + (size_t)i * 3;
        const float x = p[0], y = p[1], z = p[2];
        const float qw = fmaf(x, x, fmaf(y, y, z * z));
        const short hx = f2bf(x), hy = f2bf(y), hz = f2bf(z);
        const float fx = bf2f(hx), fy = bf2f(hy), fz = bf2f(hz);
        const short nhx = f2bf(-2.f * fx), nhy = f2bf(-2.f * fy), nhz = f2bf(-2.f * fz);
        const short nlx = f2bf(-2.f * (x - fx));
        const short nly = f2bf(-2.f * (y - fy));
        const short nlz = f2bf(-2.f * (z - fz));
        const short qwh = f2bf(qw);
        const short qwl = f2bf(qw - bf2f(qwh));
        bf16x8 h0 = {nhx, nhy, nhz, nlx, nly, nlz, qwh, qwl};
        bf16x8 h1 = {nhx, nhy, nhz, ONE, ONE, 0, 0, 0};
        Apack[2 * (size_t)i]     = h0;
        Apack[2 * (size_t)i + 1] = h1;
    } else {                              // data point -> B fragments
        const int j = i - tot0;
        const float* p = data + (size_t)j * 3;
        const float x = p[0], y = p[1], z = p[2];
        const float pw = fmaf(x, x, fmaf(y, y, z * z));
        const short hx = f2bf(x), hy = f2bf(y), hz = f2bf(z);
        const short lx = f2bf(x - bf2f(hx));
        const short ly = f2bf(y - bf2f(hy));
        const short lz = f2bf(z - bf2f(hz));
        const short pwh = f2bf(pw);
        const short pwl = f2bf(pw - bf2f(pwh));
        bf16x8 h0 = {hx, hy, hz, hx, hy, hz, ONE, ONE};
        bf16x8 h1 = {lx, ly, lz, pwh, pwl, 0, 0, 0};
        Bpack[2 * (size_t)j]     = h0;
        Bpack[2 * (size_t)j + 1] = h1;
    }
}

// Stage 1: full distance matrix on the MFMA pipe (32x32x16), mins via
// order-preserving-uint atomicMin (deterministic). Block = 64 rows x M-half;
// 4 waves split m-tile pairs; B fragments register-double-buffered.
__global__ __launch_bounds__(256, 4)
void chamfer_mfma_kernel(const bf16x8* __restrict__ Apack,
                         const bf16x8* __restrict__ Bpack,
                         unsigned* __restrict__ rowmin_u,   // [B*N]
                         unsigned* __restrict__ colmin_u,   // [B*M]
                         int N, int M, int B)
{
    const int QBL = N >> 6;
    const int blk = blockIdx.x;
    const int mh  = blk & 1;
    const int qb  = (blk >> 1) % QBL;
    const int b   = blk / (2 * QBL);
    const int lane = threadIdx.x & 63, wave = threadIdx.x >> 6;
    const int c = lane & 31, h = lane >> 5;
    const int row0 = qb * 64;
    const int Mh = M >> 1;

    const bf16x8* __restrict__ Ab = Apack + 2 * ((size_t)b * N + row0);
    const bf16x8* __restrict__ Bb = Bpack + 2 * ((size_t)b * M + (size_t)mh * Mh);

    const bf16x8 a0 = Ab[2 * c + h];
    const bf16x8 a1 = Ab[2 * (32 + c) + h];

    f32x16 rmin0, rmin1, zacc;
    #pragma unroll
    for (int r = 0; r < 16; ++r) { rmin0[r] = 3.4e38f; rmin1[r] = 3.4e38f; zacc[r] = 0.f; }

    const int PAIRS = Mh >> 6;            // 64 m-tile pairs per half
    bf16x8 B0 = Bb[(size_t)(2 * wave) * 64 + 2 * c + h];
    bf16x8 B1 = Bb[(size_t)(2 * wave + 1) * 64 + 2 * c + h];

    for (int pi = wave; pi < PAIRS; pi += 4) {
        const int pn = (pi + 4 < PAIRS) ? pi + 4 : wave;   // unconditional prefetch
        bf16x8 Bn0 = Bb[(size_t)(2 * pn) * 64 + 2 * c + h];
        bf16x8 Bn1 = Bb[(size_t)(2 * pn + 1) * 64 + 2 * c + h];

        f32x16 D00 = __builtin_amdgcn_mfma_f32_32x32x16_bf16(a0, B0, zacc, 0, 0, 0);
        f32x16 D01 = __builtin_amdgcn_mfma_f32_32x32x16_bf16(a0, B1, zacc, 0, 0, 0);
        #pragma unroll
        for (int r = 0; r < 16; ++r)
            rmin0[r] = fminf(fminf(D00[r], D01[r]), rmin0[r]);   // v_min3
        float cm0 = vmin16(D00);
        float cm1 = vmin16(D01);

        f32x16 D10 = __builtin_amdgcn_mfma_f32_32x32x16_bf16(a1, B0, zacc, 0, 0, 0);
        f32x16 D11 = __builtin_amdgcn_mfma_f32_32x32x16_bf16(a1, B1, zacc, 0, 0, 0);
        #pragma unroll
        for (int r = 0; r < 16; ++r)
            rmin1[r] = fminf(fminf(D10[r], D11[r]), rmin1[r]);
        cm0 = fminf(cm0, vmin16(D10));
        cm1 = fminf(cm1, vmin16(D11));

        cm0 = fminf(cm0, __shfl_xor(cm0, 32));
        cm1 = fminf(cm1, __shfl_xor(cm1, 32));
        if (lane < 32) {
            unsigned* cp = colmin_u + (size_t)b * M + (size_t)mh * Mh;
            atomicMin(&cp[(2 * pi) * 32 + c], fkey(cm0));
            atomicMin(&cp[(2 * pi + 1) * 32 + c], fkey(cm1));
        }
        B0 = Bn0; B1 = Bn1;
    }

    // row-mins: butterfly across the 32 col-lanes, one atomic per row
    unsigned* rp = rowmin_u + (size_t)b * N + row0;
    #pragma unroll
    for (int r = 0; r < 16; ++r) {
        const int rr = (r & 3) + 8 * (r >> 2) + 4 * h;   // m74/m101 C-layout
        float v0 = rmin0[r], v1 = rmin1[r];
        v0 = fminf(v0, __shfl_xor(v0, 1));  v1 = fminf(v1, __shfl_xor(v1, 1));
        v0 = fminf(v0, __shfl_xor(v0, 2));  v1 = fminf(v1, __shfl_xor(v1, 2));
        v0 = fminf(v0, __shfl_xor(v0, 4));  v1 = fminf(v1, __shfl_xor(v1, 4));
        v0 = fminf(v0, __shfl_xor(v0, 8));  v1 = fminf(v1, __shfl_xor(v1, 8));
        v0 = fminf(v0, __shfl_xor(v0, 16)); v1 = fminf(v1, __shfl_xor(v1, 16));
        if (c == 0) {
            atomicMin(&rp[rr],      fkey(v0));
            atomicMin(&rp[32 + rr], fkey(v1));
        }
    }
}

// Stage 2: invert keys, clamp, block-sum (minu = rowmin_u ++ colmin_u).
__global__ __launch_bounds__(256)
void chamfer_stage2(const unsigned* __restrict__ minu, float* __restrict__ bsums)
{
    __shared__ float wsum[4];
    const int gid = blockIdx.x * 256 + threadIdx.x;
    float d = fmaxf(finv(minu[gid]), 0.f);
    for (int off = 32; off; off >>= 1) d += __shfl_down(d, off);
    if ((threadIdx.x & 63) == 0) wsum[threadIdx.x >> 6] = d;
    __syncthreads();
    if (threadIdx.x == 0)
        bsums[blockIdx.x] = wsum[0] + wsum[1] + wsum[2] + wsum[3];
}

// Finalize: mean_b( max(rowsum_b/N, colsum_b/M) )
__global__ __launch_bounds__(256)
void chamfer_finalize(const float* __restrict__ bsums, float* __restrict__ out,
                      int N, int M, int B)
{
    __shared__ float smem[512];
    __shared__ float seg[16];
    const int nr = N >> 8, nc = M >> 8;
    const int nrow = B * nr, ntot = nrow + B * nc;
    const int tid = threadIdx.x;
    for (int i = tid; i < ntot; i += 256) smem[i] = bsums[i];
    __syncthreads();
    if (tid < 2 * B) {
        const int dir = tid / B, bb = tid % B;
        float s = 0.f;
        if (dir == 0) for (int i = 0; i < nr; ++i) s += smem[bb * nr + i];
        else          for (int i = 0; i < nc; ++i) s += smem[nrow + bb * nc + i];
        seg[tid] = s;
    }
    __syncthreads();
    if (tid == 0) {
        float acc = 0.f;
        for (int bb = 0; bb < B; ++bb)
            acc += fmaxf(seg[bb] / (float)N, seg[B + bb] / (float)M);
        out[0] = acc / (float)B;
    }
}

extern "C" void kernel_launch(void* const* d_in, const int* in_sizes, int n_in,
                              void* d_out, int out_size, void* d_ws, size_t ws_size,
                              hipStream_t stream)
{
    const float* rec  = (const float*)d_in[0];
    const float* data = (const float*)d_in[1];
    const int B = 4;
    const int N = in_sizes[0] / (B * 3);
    const int M = in_sizes[1] / (B * 3);
    const int tot = B * (N + M);

    // ws: Apack 1MB | Bpack 1MB | minu 256KB | bsums 1KB  (total ~2.3 MB)
    char* w = (char*)d_ws;
    bf16x8* Apack = (bf16x8*)w;     w += (size_t)B * N * 2 * sizeof(bf16x8);
    bf16x8* Bpack = (bf16x8*)w;     w += (size_t)B * M * 2 * sizeof(bf16x8);
    unsigned* minu = (unsigned*)w;  w += (size_t)tot * sizeof(unsigned);
    float* bsums = (float*)w;
    unsigned* rowmin_u = minu;
    unsigned* colmin_u = minu + (size_t)B * N;

    hipMemsetAsync(minu, 0xFF, (size_t)tot * sizeof(unsigned), stream);
    chamfer_prep<<<(tot + 255) / 256, 256, 0, stream>>>(rec, data, Apack, Bpack,
                                                        N, M, B);
    chamfer_mfma_kernel<<<B * (N >> 6) * 2, 256, 0, stream>>>(Apack, Bpack,
                                                              rowmin_u, colmin_u,
                                                              N, M, B);
    chamfer_stage2<<<tot / 256, 256, 0, stream>>>(minu, bsums);
    chamfer_finalize<<<1, 256, 0, stream>>>(bsums, (float*)d_out, N, M, B);
}

// Round 12
// 48.602 us; speedup vs baseline: 1.6900x; 1.2816x over previous
//
#include <hip/hip_runtime.h>

typedef float f32x16 __attribute__((ext_vector_type(16)));
typedef short bf16x8 __attribute__((ext_vector_type(8)));

constexpr int SROWS  = 256;   // stationary rows per block (8 fragments)
constexpr int NSLICE = 4;     // streaming slices per pass

__device__ inline short f2bf(float x) {               // RNE float->bf16 bits
    unsigned u = __float_as_uint(x);
    unsigned r = (u + 0x7fffu + ((u >> 16) & 1u)) >> 16;
    return (short)r;
}
__device__ inline float bf2f(short h) {
    return __uint_as_float(((unsigned)(unsigned short)h) << 16);
}
__device__ inline float vmin16(f32x16 v) {
    float a = fminf(fminf(v[0], v[1]), fminf(v[2], v[3]));
    float b = fminf(fminf(v[4], v[5]), fminf(v[6], v[7]));
    float c = fminf(fminf(v[8], v[9]), fminf(v[10], v[11]));
    float d = fminf(fminf(v[12], v[13]), fminf(v[14], v[15]));
    return fminf(fminf(a, b), fminf(c, d));
}

// K-slot map (k = 8*half + j), d = qw + pw - 2(qh+ql).(ph+pl) [ql.pl dropped]:
// A(query role) h0={-2qh(3), -2ql(3), qwh, qwl}  h1={-2qh(3), 1, 1, 0,0,0}
// B(point role) h0={ph(3), ph(3), 1, 1}          h1={pl(3), pwh, pwl, 0,0,0}
// A and B share one (half,j) slot space -> mapping-agnostic (r11: absmax 0.0).
// Every point gets BOTH packings (query-role for its pass-as-stationary,
// point-role for its pass-as-streaming).
__global__ __launch_bounds__(256)
void chamfer_prep(const float* __restrict__ rec, const float* __restrict__ data,
                  bf16x8* __restrict__ Ar, bf16x8* __restrict__ Br,
                  bf16x8* __restrict__ Ad, bf16x8* __restrict__ Bd,
                  int N, int M, int B)
{
    const int i = blockIdx.x * 256 + threadIdx.x;
    const int tot0 = B * N, tot = tot0 + B * M;
    if (i >= tot) return;
    const short ONE = 0x3F80;
    const bool isRec = i < tot0;
    const int j = isRec ? i : i - tot0;
    const float* p = (isRec ? rec : data) + (size_t)j * 3;
    const float x = p[0], y = p[1], z = p[2];
    const float w = fmaf(x, x, fmaf(y, y, z * z));
    const short hx = f2bf(x), hy = f2bf(y), hz = f2bf(z);
    const float fx = bf2f(hx), fy = bf2f(hy), fz = bf2f(hz);
    const short nhx = f2bf(-2.f * fx), nhy = f2bf(-2.f * fy), nhz = f2bf(-2.f * fz);
    const short nlx = f2bf(-2.f * (x - fx));
    const short nly = f2bf(-2.f * (y - fy));
    const short nlz = f2bf(-2.f * (z - fz));
    const short lx = f2bf(x - fx), ly = f2bf(y - fy), lz = f2bf(z - fz);
    const short wh = f2bf(w);
    const short wl = f2bf(w - bf2f(wh));

    bf16x8 A0 = {nhx, nhy, nhz, nlx, nly, nlz, wh, wl};
    bf16x8 A1 = {nhx, nhy, nhz, ONE, ONE, 0, 0, 0};
    bf16x8 B0 = {hx, hy, hz, hx, hy, hz, ONE, ONE};
    bf16x8 B1 = {lx, ly, lz, wh, wl, 0, 0, 0};

    bf16x8* Adst = (isRec ? Ar : Ad) + 2 * (size_t)j;
    bf16x8* Bdst = (isRec ? Br : Bd) + 2 * (size_t)j;
    Adst[0] = A0; Adst[1] = A1;
    Bdst[0] = B0; Bdst[1] = B1;
}

// Stage 1: two symmetric passes over the distance matrix (32x32x16 MFMA).
// Block = (pass, batch, stationary-256-tile, streaming-slice). Per streaming
// 32-col tile: 8 MFMAs vs the 8 stationary fragments; in-lane vmin16 over
// D-regs + xor32 completes the min-over-stationary -> ONE coalesced store.
// No atomics, no butterflies, no LDS.
__global__ __launch_bounds__(256, 4)
void chamfer_mfma_kernel(const bf16x8* __restrict__ Ar, const bf16x8* __restrict__ Bd,
                         const bf16x8* __restrict__ Ad, const bf16x8* __restrict__ Br,
                         float* __restrict__ part_data,   // [B][N/256][M]
                         float* __restrict__ part_rec,    // [B][M/256][N]
                         int N, int M, int B)
{
    const int nSB1 = N / SROWS;
    const int G1   = B * nSB1 * NSLICE;

    const bf16x8* Ap; const bf16x8* Bp; float* outp;
    int S, T, idx;
    if ((int)blockIdx.x < G1) {
        Ap = Ar; Bp = Bd; outp = part_data; S = N; T = M; idx = blockIdx.x;
    } else {
        Ap = Ad; Bp = Br; outp = part_rec;  S = M; T = N; idx = blockIdx.x - G1;
    }
    const int nSB = S / SROWS;
    const int sl  = idx % NSLICE; idx /= NSLICE;
    const int sb  = idx % nSB;
    const int b   = idx / nSB;

    const int lane = threadIdx.x & 63, wave = threadIdx.x >> 6;
    const int c = lane & 31, h = lane >> 5;

    const bf16x8* __restrict__ Ab = Ap + 2 * ((size_t)b * S + sb * SROWS);
    const bf16x8* __restrict__ Bb = Bp + 2 * ((size_t)b * T);
    float* __restrict__ outBase = outp + ((size_t)b * nSB + sb) * T;

    bf16x8 a[8];
    #pragma unroll
    for (int f = 0; f < 8; ++f) a[f] = Ab[2 * (f * 32 + c) + h];

    f32x16 zacc;
    #pragma unroll
    for (int r = 0; r < 16; ++r) zacc[r] = 0.f;

    const int TS32 = (T / NSLICE) >> 5;          // 32-col tiles per slice
    const int t0   = sl * TS32 + wave;
    const int tEnd = (sl + 1) * TS32;

    bf16x8 bcur = Bb[2 * ((size_t)t0 * 32 + c) + h];
    for (int t = t0; t < tEnd; t += 4) {
        int tn = t + 4; if (tn >= tEnd) tn = t0;           // safe wrap
        bf16x8 bnext = Bb[2 * ((size_t)tn * 32 + c) + h];  // one-ahead prefetch

        f32x16 d0 = __builtin_amdgcn_mfma_f32_32x32x16_bf16(a[0], bcur, zacc, 0, 0, 0);
        f32x16 d1 = __builtin_amdgcn_mfma_f32_32x32x16_bf16(a[1], bcur, zacc, 0, 0, 0);
        float m0 = fminf(vmin16(d0), vmin16(d1));
        f32x16 d2 = __builtin_amdgcn_mfma_f32_32x32x16_bf16(a[2], bcur, zacc, 0, 0, 0);
        f32x16 d3 = __builtin_amdgcn_mfma_f32_32x32x16_bf16(a[3], bcur, zacc, 0, 0, 0);
        float m1 = fminf(vmin16(d2), vmin16(d3));
        f32x16 d4 = __builtin_amdgcn_mfma_f32_32x32x16_bf16(a[4], bcur, zacc, 0, 0, 0);
        f32x16 d5 = __builtin_amdgcn_mfma_f32_32x32x16_bf16(a[5], bcur, zacc, 0, 0, 0);
        float m2 = fminf(vmin16(d4), vmin16(d5));
        f32x16 d6 = __builtin_amdgcn_mfma_f32_32x32x16_bf16(a[6], bcur, zacc, 0, 0, 0);
        f32x16 d7 = __builtin_amdgcn_mfma_f32_32x32x16_bf16(a[7], bcur, zacc, 0, 0, 0);
        float m3 = fminf(vmin16(d6), vmin16(d7));

        float cm = fminf(fminf(m0, m1), fminf(m2, m3));    // min over 128 rows (h-half)
        cm = fminf(cm, __shfl_xor(cm, 32));                // merge halves: 256 rows
        if (lane < 32)
            outBase[(size_t)t * 32 + c] = cm;              // 128B coalesced store
        bcur = bnext;
    }
}

// Stage 2: per query, min over the nSB stationary-block partials, clamp, sum.
__global__ __launch_bounds__(256)
void chamfer_stage2(const float* __restrict__ part_data,
                    const float* __restrict__ part_rec,
                    float* __restrict__ bsums, int N, int M, int B)
{
    __shared__ float wsum[4];
    const int gid = blockIdx.x * 256 + threadIdx.x;
    const int nD = B * M;

    const float* base; size_t stride; int depth;
    if (gid < nD) {
        const int b = gid / M, col = gid - b * M;
        base = part_data + ((size_t)b * (N / SROWS)) * M + col;
        stride = M; depth = N / SROWS;
    } else {
        const int g = gid - nD;
        const int b = g / N, col = g - b * N;
        base = part_rec + ((size_t)b * (M / SROWS)) * N + col;
        stride = N; depth = M / SROWS;
    }
    float m0 = 3.4e38f, m1 = 3.4e38f, m2 = 3.4e38f, m3 = 3.4e38f;
    int s = 0;
    for (; s + 4 <= depth; s += 4) {
        m0 = fminf(m0, base[(s + 0) * stride]);
        m1 = fminf(m1, base[(s + 1) * stride]);
        m2 = fminf(m2, base[(s + 2) * stride]);
        m3 = fminf(m3, base[(s + 3) * stride]);
    }
    for (; s < depth; ++s) m0 = fminf(m0, base[s * stride]);
    float d = fmaxf(fminf(fminf(m0, m1), fminf(m2, m3)), 0.f);

    for (int off = 32; off; off >>= 1) d += __shfl_down(d, off);
    if ((threadIdx.x & 63) == 0) wsum[threadIdx.x >> 6] = d;
    __syncthreads();
    if (threadIdx.x == 0)
        bsums[blockIdx.x] = wsum[0] + wsum[1] + wsum[2] + wsum[3];
}

// Finalize: mean_b( max(recsum_b/N, datasum_b/M) )
__global__ __launch_bounds__(256)
void chamfer_finalize(const float* __restrict__ bsums, float* __restrict__ out,
                      int N, int M, int B)
{
    __shared__ float smem[512];
    __shared__ float seg[16];
    const int ncD = M >> 8, ncR = N >> 8;       // stage2 blocks per batch
    const int nD  = B * ncD, ntot = nD + B * ncR;
    const int tid = threadIdx.x;
    for (int i = tid; i < ntot; i += 256) smem[i] = bsums[i];
    __syncthreads();
    if (tid < 2 * B) {
        const int dir = tid / B, bb = tid % B;   // dir0 = data, dir1 = rec
        float s = 0.f;
        if (dir == 0) for (int i = 0; i < ncD; ++i) s += smem[bb * ncD + i];
        else          for (int i = 0; i < ncR; ++i) s += smem[nD + bb * ncR + i];
        seg[tid] = s;
    }
    __syncthreads();
    if (tid == 0) {
        float acc = 0.f;
        for (int bb = 0; bb < B; ++bb)
            acc += fmaxf(seg[B + bb] / (float)N, seg[bb] / (float)M);
        out[0] = acc / (float)B;
    }
}

extern "C" void kernel_launch(void* const* d_in, const int* in_sizes, int n_in,
                              void* d_out, int out_size, void* d_ws, size_t ws_size,
                              hipStream_t stream)
{
    const float* rec  = (const float*)d_in[0];
    const float* data = (const float*)d_in[1];
    const int B = 4;
    const int N = in_sizes[0] / (B * 3);
    const int M = in_sizes[1] / (B * 3);
    const int tot = B * (N + M);

    // ws: Ar 1MB | Br 1MB | Ad 1MB | Bd 1MB | part_data 4MB | part_rec 4MB | bsums
    char* w = (char*)d_ws;
    bf16x8* Ar = (bf16x8*)w;  w += (size_t)B * N * 2 * sizeof(bf16x8);
    bf16x8* Br = (bf16x8*)w;  w += (size_t)B * N * 2 * sizeof(bf16x8);
    bf16x8* Ad = (bf16x8*)w;  w += (size_t)B * M * 2 * sizeof(bf16x8);
    bf16x8* Bd = (bf16x8*)w;  w += (size_t)B * M * 2 * sizeof(bf16x8);
    float* part_data = (float*)w;  w += (size_t)B * (N / SROWS) * M * sizeof(float);
    float* part_rec  = (float*)w;  w += (size_t)B * (M / SROWS) * N * sizeof(float);
    float* bsums = (float*)w;

    chamfer_prep<<<(tot + 255) / 256, 256, 0, stream>>>(rec, data, Ar, Br, Ad, Bd,
                                                        N, M, B);
    const int G = B * (N / SROWS) * NSLICE + B * (M / SROWS) * NSLICE;
    chamfer_mfma_kernel<<<G, 256, 0, stream>>>(Ar, Bd, Ad, Br,
                                               part_data, part_rec, N, M, B);
    chamfer_stage2<<<tot / 256, 256, 0, stream>>>(part_data, part_rec, bsums,
                                                  N, M, B);
    chamfer_finalize<<<1, 256, 0, stream>>>(bsums, (float*)d_out, N, M, B);
}